// Round 5
// baseline (293.788 us; speedup 1.0000x reference)
//
#include <hip/hip_runtime.h>

constexpr int N_NODES = 50000;
constexpr int N_EDGES = 800000;
constexpr int D = 64;

constexpr int NREG = 256;            // regions == gather blocks
constexpr int RSZ = 196;             // nodes per region (256*196 = 50176 >= 50000)
constexpr int SUBS = 4;              // sub-bins per region (atomic contention /4)
constexpr int SUBCAP = 1024;         // mean 784, sigma 28 -> 8.5 sigma headroom
constexpr int RCAP = SUBS * SUBCAP;  // 4096 packed edges per region

// Workspace layout (ints):
//   rcnt [NREG*SUBS]         at +0        (4 KB, memset each call)
//   rbuf [NREG*RCAP]         at +1024     (4 MB)
//   hb   [N_NODES*D ushorts] at byte 4198400  (6.4 MB)
constexpr int WS_RCNT = 0;
constexpr int WS_RBUF = 1024;
constexpr size_t WS_HB_BYTES = (size_t)(1024 + NREG * RCAP) * 4;

// feat (fp32) -> bf16 copy for the gather path (halves gather bytes).
__global__ __launch_bounds__(256) void tobf16_kernel(
    const float4* __restrict__ feat4, ushort* __restrict__ hb) {
  int t = blockIdx.x * 256 + threadIdx.x;
  if (t >= N_NODES * D / 4) return;
  float4 f = feat4[t];
  ushort4 h;
  unsigned u;
  u = __float_as_uint(f.x); u += 0x7FFF + ((u >> 16) & 1); h.x = u >> 16;  // RNE
  u = __float_as_uint(f.y); u += 0x7FFF + ((u >> 16) & 1); h.y = u >> 16;
  u = __float_as_uint(f.z); u += 0x7FFF + ((u >> 16) & 1); h.z = u >> 16;
  u = __float_as_uint(f.w); u += 0x7FFF + ((u >> 16) & 1); h.w = u >> 16;
  *reinterpret_cast<ushort4*>(hb + t * 4) = h;
}

// Bin edges by destination region: packed word = (dst_local << 16) | src.
__device__ __forceinline__ void bin_one(int d, int s, int sub,
                                        int* rcnt, unsigned* rbuf) {
  int r = d / RSZ;  // compiler emits magic-mul
  unsigned pk = ((unsigned)(d - r * RSZ) << 16) | (unsigned)s;
  int p = atomicAdd(&rcnt[(r << 2) + sub], 1);
  if (p < SUBCAP) rbuf[r * RCAP + sub * SUBCAP + p] = pk;
}

__global__ __launch_bounds__(256) void bin_kernel(
    const int* __restrict__ src, const int* __restrict__ dst,
    int* __restrict__ rcnt, unsigned* __restrict__ rbuf) {
  int t = blockIdx.x * 256 + threadIdx.x;
  if (t * 4 >= N_EDGES) return;
  const int4 d4 = reinterpret_cast<const int4*>(dst)[t];
  const int4 s4 = reinterpret_cast<const int4*>(src)[t];
  bin_one(d4.x, s4.x, 0, rcnt, rbuf);
  bin_one(d4.y, s4.y, 1, rcnt, rbuf);
  bin_one(d4.z, s4.z, 2, rcnt, rbuf);
  bin_one(d4.w, s4.w, 3, rcnt, rbuf);
}

// One block per region: LDS counting-sort of the region's edges by local
// dst, then per-node register gather-accumulate (bf16 neighbors, fp32 acc),
// residual, and Linear via width-16 shuffles. 1024 threads = 64 groups x 16.
__global__ __launch_bounds__(1024) void gin_fused_kernel(
    const float* __restrict__ feat, const ushort* __restrict__ hb,
    const float* __restrict__ W, const float* __restrict__ b,
    const float* __restrict__ eps, const int* __restrict__ rcnt,
    const unsigned* __restrict__ rbuf, float* __restrict__ out) {
  __shared__ float Wt[D * D];        // Wt[i*64+o] = W[o*64+i]
  __shared__ unsigned sorted[RCAP];  // region edges sorted by local dst (src only)
  __shared__ int hist[RSZ];
  __shared__ int start[RSZ + 1];
  __shared__ int cursor[RSZ];
  __shared__ int scan_tmp[256];

  int tid = threadIdx.x;
  int r = blockIdx.x;

  // Stage W transposed; contiguous LDS writes (conflict-free), strided
  // global reads absorbed by L1/L2 (W is 16 KB).
  for (int q = tid; q < D * D; q += 1024) {
    Wt[q] = W[((q & 63) << 6) + (q >> 6)];
  }
  if (tid < RSZ) hist[tid] = 0;
  __syncthreads();

  int base = r * RCAP;
  int cs[SUBS];
#pragma unroll
  for (int sub = 0; sub < SUBS; ++sub) {
    int c = rcnt[(r << 2) + sub];
    cs[sub] = (c > SUBCAP) ? SUBCAP : c;
  }

  // Pass 1: histogram by local dst.
#pragma unroll
  for (int sub = 0; sub < SUBS; ++sub) {
    for (int e = tid; e < cs[sub]; e += 1024) {
      unsigned pk = rbuf[base + sub * SUBCAP + e];
      atomicAdd(&hist[pk >> 16], 1);
    }
  }
  __syncthreads();

  // Exclusive scan of hist -> start/cursor (first 256 threads).
  if (tid < 256) scan_tmp[tid] = (tid < RSZ) ? hist[tid] : 0;
  __syncthreads();
  for (int ofs = 1; ofs < 256; ofs <<= 1) {
    int v = 0;
    if (tid < 256 && tid >= ofs) v = scan_tmp[tid - ofs];
    __syncthreads();
    if (tid < 256) scan_tmp[tid] += v;
    __syncthreads();
  }
  if (tid < RSZ) {
    int ex = scan_tmp[tid] - hist[tid];
    start[tid] = ex;
    cursor[tid] = ex;
  }
  if (tid == RSZ - 1) start[RSZ] = scan_tmp[RSZ - 1];
  __syncthreads();

  // Pass 2: scatter src indices into sorted[] by local dst.
#pragma unroll
  for (int sub = 0; sub < SUBS; ++sub) {
    for (int e = tid; e < cs[sub]; e += 1024) {
      unsigned pk = rbuf[base + sub * SUBCAP + e];
      int p = atomicAdd(&cursor[pk >> 16], 1);
      sorted[p] = pk & 0xFFFFu;
    }
  }
  __syncthreads();

  // Per-node gather + residual + matvec. Group g owns nodes g, g+64, ...
  int g = tid >> 4;
  int l = tid & 15;
  int j4 = l << 2;
  float s = 1.0f + eps[0];

  for (int n = g; n < RSZ; n += 64) {
    int node = r * RSZ + n;
    if (node >= N_NODES) continue;  // group-uniform predicate

    float4 acc = *reinterpret_cast<const float4*>(feat + (node << 6) + j4);
    acc.x *= s; acc.y *= s; acc.z *= s; acc.w *= s;

    int e = start[n], e1 = start[n + 1];
    for (; e + 4 <= e1; e += 4) {
      int sa = sorted[e], sb = sorted[e + 1], sc = sorted[e + 2], sd = sorted[e + 3];
      ushort4 ha = *reinterpret_cast<const ushort4*>(hb + (sa << 6) + j4);
      ushort4 hbv = *reinterpret_cast<const ushort4*>(hb + (sb << 6) + j4);
      ushort4 hc = *reinterpret_cast<const ushort4*>(hb + (sc << 6) + j4);
      ushort4 hd = *reinterpret_cast<const ushort4*>(hb + (sd << 6) + j4);
      acc.x += __uint_as_float((unsigned)ha.x << 16) + __uint_as_float((unsigned)hbv.x << 16)
             + __uint_as_float((unsigned)hc.x << 16) + __uint_as_float((unsigned)hd.x << 16);
      acc.y += __uint_as_float((unsigned)ha.y << 16) + __uint_as_float((unsigned)hbv.y << 16)
             + __uint_as_float((unsigned)hc.y << 16) + __uint_as_float((unsigned)hd.y << 16);
      acc.z += __uint_as_float((unsigned)ha.z << 16) + __uint_as_float((unsigned)hbv.z << 16)
             + __uint_as_float((unsigned)hc.z << 16) + __uint_as_float((unsigned)hd.z << 16);
      acc.w += __uint_as_float((unsigned)ha.w << 16) + __uint_as_float((unsigned)hbv.w << 16)
             + __uint_as_float((unsigned)hc.w << 16) + __uint_as_float((unsigned)hd.w << 16);
    }
    for (; e < e1; ++e) {
      int sn = sorted[e];
      ushort4 h = *reinterpret_cast<const ushort4*>(hb + (sn << 6) + j4);
      acc.x += __uint_as_float((unsigned)h.x << 16);
      acc.y += __uint_as_float((unsigned)h.y << 16);
      acc.z += __uint_as_float((unsigned)h.z << 16);
      acc.w += __uint_as_float((unsigned)h.w << 16);
    }

    // out[node][j4..j4+3] = b + sum_i rst[i] * Wt[i*64 + o]
    float4 res = *reinterpret_cast<const float4*>(b + j4);
#pragma unroll
    for (int i4 = 0; i4 < 16; ++i4) {
      float rx = __shfl(acc.x, i4, 16);
      float ry = __shfl(acc.y, i4, 16);
      float rz = __shfl(acc.z, i4, 16);
      float rw = __shfl(acc.w, i4, 16);
      const float4 w0 = *reinterpret_cast<const float4*>(Wt + ((i4 << 2) + 0) * D + j4);
      const float4 w1 = *reinterpret_cast<const float4*>(Wt + ((i4 << 2) + 1) * D + j4);
      const float4 w2 = *reinterpret_cast<const float4*>(Wt + ((i4 << 2) + 2) * D + j4);
      const float4 w3 = *reinterpret_cast<const float4*>(Wt + ((i4 << 2) + 3) * D + j4);
      res.x += rx * w0.x + ry * w1.x + rz * w2.x + rw * w3.x;
      res.y += rx * w0.y + ry * w1.y + rz * w2.y + rw * w3.y;
      res.z += rx * w0.z + ry * w1.z + rz * w2.z + rw * w3.z;
      res.w += rx * w0.w + ry * w1.w + rz * w2.w + rw * w3.w;
    }
    *reinterpret_cast<float4*>(out + (node << 6) + j4) = res;
  }
}

extern "C" void kernel_launch(void* const* d_in, const int* in_sizes, int n_in,
                              void* d_out, int out_size, void* d_ws, size_t ws_size,
                              hipStream_t stream) {
  const float* feat = (const float*)d_in[0];
  const float* W    = (const float*)d_in[1];
  const float* b    = (const float*)d_in[2];
  const float* eps  = (const float*)d_in[3];
  const int*   src  = (const int*)d_in[4];
  const int*   dst  = (const int*)d_in[5];
  float* out = (float*)d_out;

  int* ws = (int*)d_ws;
  int* rcnt      = ws + WS_RCNT;
  unsigned* rbuf = (unsigned*)(ws + WS_RBUF);
  ushort* hb     = (ushort*)((char*)d_ws + WS_HB_BYTES);

  hipMemsetAsync(rcnt, 0, NREG * SUBS * sizeof(int), stream);
  hipLaunchKernelGGL(tobf16_kernel, dim3((N_NODES * D / 4 + 255) / 256), dim3(256),
                     0, stream, (const float4*)feat, hb);
  hipLaunchKernelGGL(bin_kernel, dim3((N_EDGES / 4 + 255) / 256), dim3(256), 0,
                     stream, src, dst, rcnt, rbuf);
  hipLaunchKernelGGL(gin_fused_kernel, dim3(NREG), dim3(1024), 0, stream,
                     feat, hb, W, b, eps, rcnt, rbuf, out);
}

// Round 6
// 137.120 us; speedup vs baseline: 2.1426x; 2.1426x over previous
//
#include <hip/hip_runtime.h>

constexpr int N_NODES = 50000;
constexpr int N_EDGES = 800000;
constexpr int D = 64;

constexpr int NREG = 256;                         // destination regions
constexpr int RSZ = 196;                          // nodes per region (256*196 >= 50000)
constexpr int EPB = 4096;                         // edges per bin block
constexpr int NBINB = (N_EDGES + EPB - 1) / EPB;  // 196 bin blocks
constexpr int CELLCAP = 64;   // per-(block,region) cell cap; mean 16, P(>64) ~ 1e-20
constexpr int RECAP = 4608;   // per-region CSR cap; mean 3136, sigma 56 (26 sigma)

// Workspace layout:
//   cnt2 [NBINB*NREG] ints      at int    0        (200 KB, fully written each call)
//   noff [N_NODES]    ints      at int    50176
//   ndeg [N_NODES]    ints      at int    100176
//   rbuf [NBINB*NREG*CELLCAP]   at int    150272   (12.8 MB, 256B-aligned cells)
//   csr  [NREG*RECAP] ushorts   at byte   13446144 (2.4 MB)
//   hb   [N_NODES*D]  ushorts   at byte   15805440 (6.4 MB)
constexpr int WS_CNT2 = 0;
constexpr int WS_NOFF = 50176;
constexpr int WS_NDEG = 100176;
constexpr int WS_RBUF = 150272;
constexpr size_t WS_CSR_BYTE = (size_t)(WS_RBUF + NBINB * NREG * CELLCAP) * 4;
constexpr size_t WS_HB_BYTE = WS_CSR_BYTE + (size_t)NREG * RECAP * 2;

// feat (fp32) -> bf16 copy for the gather path (halves gather bytes).
__global__ __launch_bounds__(256) void tobf16_kernel(
    const float4* __restrict__ feat4, ushort* __restrict__ hb) {
  int t = blockIdx.x * 256 + threadIdx.x;
  if (t >= N_NODES * D / 4) return;
  float4 f = feat4[t];
  ushort4 h;
  unsigned u;
  u = __float_as_uint(f.x); u += 0x7FFF + ((u >> 16) & 1); h.x = u >> 16;  // RNE
  u = __float_as_uint(f.y); u += 0x7FFF + ((u >> 16) & 1); h.y = u >> 16;
  u = __float_as_uint(f.z); u += 0x7FFF + ((u >> 16) & 1); h.z = u >> 16;
  u = __float_as_uint(f.w); u += 0x7FFF + ((u >> 16) & 1); h.w = u >> 16;
  *reinterpret_cast<ushort4*>(hb + t * 4) = h;
}

// Bin 4096 edges per block: LDS counting-sort by region, write each region's
// run to a private (block,region) cell. NO global atomics, whole-line writes.
__global__ __launch_bounds__(1024) void bin_kernel(
    const int* __restrict__ src, const int* __restrict__ dst,
    int* __restrict__ cnt2, unsigned* __restrict__ rbuf) {
  __shared__ unsigned sorted[EPB];
  __shared__ int hist[NREG], start[NREG], cursor[NREG], scan_tmp[NREG];
  int tid = threadIdx.x, blk = blockIdx.x;
  if (tid < NREG) hist[tid] = 0;
  __syncthreads();

  int e0 = blk * EPB + tid * 4;
  bool valid = (e0 + 4 <= N_EDGES);  // N_EDGES % 4 == 0
  unsigned pk[4];
  int rg[4];
  if (valid) {
    const int4 d4 = *reinterpret_cast<const int4*>(dst + e0);
    const int4 s4 = *reinterpret_cast<const int4*>(src + e0);
    const int dd[4] = {d4.x, d4.y, d4.z, d4.w};
    const int ss[4] = {s4.x, s4.y, s4.z, s4.w};
#pragma unroll
    for (int k = 0; k < 4; ++k) {
      int r = dd[k] / RSZ;  // magic-mul
      rg[k] = r;
      pk[k] = ((unsigned)(dd[k] - r * RSZ) << 16) | (unsigned)ss[k];
      atomicAdd(&hist[r], 1);
    }
  }
  __syncthreads();
  if (tid < NREG) scan_tmp[tid] = hist[tid];
  __syncthreads();
  for (int ofs = 1; ofs < NREG; ofs <<= 1) {
    int v = 0;
    if (tid < NREG && tid >= ofs) v = scan_tmp[tid - ofs];
    __syncthreads();
    if (tid < NREG) scan_tmp[tid] += v;
    __syncthreads();
  }
  if (tid < NREG) {
    int ex = scan_tmp[tid] - hist[tid];
    start[tid] = ex;
    cursor[tid] = ex;
  }
  __syncthreads();
  if (valid) {
#pragma unroll
    for (int k = 0; k < 4; ++k) {
      int p = atomicAdd(&cursor[rg[k]], 1);
      sorted[p] = pk[k];
    }
  }
  __syncthreads();
  // Write cells: 4 threads per region; 256B-aligned bases, ~1 line per cell.
  int r = tid >> 2, sub = tid & 3;
  int c = hist[r];
  if (c > CELLCAP) c = CELLCAP;
  if (sub == 0) cnt2[blk * NREG + r] = c;
  int gbase = (blk * NREG + r) * CELLCAP;
  int lbase = start[r];
  for (int i = sub; i < c; i += 4) rbuf[gbase + i] = sorted[lbase + i];
}

// One block per region: concatenate the region's 196 cells in LDS, counting-
// sort by local node, emit per-node ushort CSR + per-node offset/degree.
__global__ __launch_bounds__(256) void compact_kernel(
    const int* __restrict__ cnt2, const unsigned* __restrict__ rbuf,
    ushort* __restrict__ csr, int* __restrict__ noff, int* __restrict__ ndeg) {
  __shared__ unsigned ebuf[RECAP];
  __shared__ int scan_tmp[256];
  __shared__ int cellstart[NBINB];
  __shared__ int hist[RSZ], nstart[RSZ], cursor[RSZ];
  __shared__ int Tsh;
  int tid = threadIdx.x, r = blockIdx.x;

  int c = (tid < NBINB) ? cnt2[tid * NREG + r] : 0;
  scan_tmp[tid] = c;
  if (tid < RSZ) hist[tid] = 0;
  __syncthreads();
  for (int ofs = 1; ofs < 256; ofs <<= 1) {
    int v = (tid >= ofs) ? scan_tmp[tid - ofs] : 0;
    __syncthreads();
    scan_tmp[tid] += v;
    __syncthreads();
  }
  if (tid < NBINB) cellstart[tid] = scan_tmp[tid] - c;
  if (tid == NBINB - 1) Tsh = scan_tmp[tid];
  __syncthreads();
  int T = Tsh;
  if (T > RECAP) T = RECAP;  // astronomically unlikely
  if (tid < NBINB) {
    int base = (tid * NREG + r) * CELLCAP;  // 16B-aligned (CELLCAP*4 = 256B)
    int cs = cellstart[tid];
    int i = 0;
    for (; i + 4 <= c; i += 4) {
      const uint4 v = *reinterpret_cast<const uint4*>(rbuf + base + i);
      if (cs + i + 3 < RECAP) {
        ebuf[cs + i + 0] = v.x; ebuf[cs + i + 1] = v.y;
        ebuf[cs + i + 2] = v.z; ebuf[cs + i + 3] = v.w;
      }
    }
    for (; i < c; ++i)
      if (cs + i < RECAP) ebuf[cs + i] = rbuf[base + i];
  }
  __syncthreads();
  for (int e = tid; e < T; e += 256) atomicAdd(&hist[ebuf[e] >> 16], 1);
  __syncthreads();
  scan_tmp[tid] = (tid < RSZ) ? hist[tid] : 0;
  __syncthreads();
  for (int ofs = 1; ofs < 256; ofs <<= 1) {
    int v = (tid >= ofs) ? scan_tmp[tid - ofs] : 0;
    __syncthreads();
    scan_tmp[tid] += v;
    __syncthreads();
  }
  if (tid < RSZ) {
    int ex = scan_tmp[tid] - hist[tid];
    nstart[tid] = ex;
    cursor[tid] = ex;
  }
  __syncthreads();
  int rbase = r * RECAP;
  for (int e = tid; e < T; e += 256) {
    unsigned pk = ebuf[e];
    int p = atomicAdd(&cursor[pk >> 16], 1);
    csr[rbase + p] = (ushort)(pk & 0xFFFFu);
  }
  if (tid < RSZ) {
    int node = r * RSZ + tid;
    if (node < N_NODES) {
      noff[node] = rbase + nstart[tid];
      ndeg[node] = hist[tid];
    }
  }
}

// Gather + residual + Linear. 3125 blocks x 256 threads = 16 nodes x 16 lanes.
__global__ __launch_bounds__(256) void gin_kernel(
    const float* __restrict__ feat, const ushort* __restrict__ hb,
    const float* __restrict__ W, const float* __restrict__ b,
    const float* __restrict__ eps, const int* __restrict__ noff,
    const int* __restrict__ ndeg, const ushort* __restrict__ csr,
    float* __restrict__ out) {
  __shared__ float Wt[D * D];  // Wt[i*64+o] = W[o*64+i]
  int tid = threadIdx.x;
  for (int q = tid; q < D * D; q += 256) Wt[q] = W[((q & 63) << 6) + (q >> 6)];
  __syncthreads();

  int ln = tid >> 4, j4 = (tid & 15) << 2;
  int node = blockIdx.x * 16 + ln;  // 3125*16 == 50000
  float s = 1.0f + eps[0];
  float4 acc = *reinterpret_cast<const float4*>(feat + (node << 6) + j4);
  acc.x *= s; acc.y *= s; acc.z *= s; acc.w *= s;

  int deg = ndeg[node];
  const ushort* ep = csr + noff[node];
  int e = 0;
  for (; e + 4 <= deg; e += 4) {
    int sa = ep[e], sb = ep[e + 1], sc = ep[e + 2], sd = ep[e + 3];
    ushort4 h0 = *reinterpret_cast<const ushort4*>(hb + (sa << 6) + j4);
    ushort4 h1 = *reinterpret_cast<const ushort4*>(hb + (sb << 6) + j4);
    ushort4 h2 = *reinterpret_cast<const ushort4*>(hb + (sc << 6) + j4);
    ushort4 h3 = *reinterpret_cast<const ushort4*>(hb + (sd << 6) + j4);
    acc.x += __uint_as_float((unsigned)h0.x << 16) + __uint_as_float((unsigned)h1.x << 16)
           + __uint_as_float((unsigned)h2.x << 16) + __uint_as_float((unsigned)h3.x << 16);
    acc.y += __uint_as_float((unsigned)h0.y << 16) + __uint_as_float((unsigned)h1.y << 16)
           + __uint_as_float((unsigned)h2.y << 16) + __uint_as_float((unsigned)h3.y << 16);
    acc.z += __uint_as_float((unsigned)h0.z << 16) + __uint_as_float((unsigned)h1.z << 16)
           + __uint_as_float((unsigned)h2.z << 16) + __uint_as_float((unsigned)h3.z << 16);
    acc.w += __uint_as_float((unsigned)h0.w << 16) + __uint_as_float((unsigned)h1.w << 16)
           + __uint_as_float((unsigned)h2.w << 16) + __uint_as_float((unsigned)h3.w << 16);
  }
  for (; e < deg; ++e) {
    int sn = ep[e];
    ushort4 h = *reinterpret_cast<const ushort4*>(hb + (sn << 6) + j4);
    acc.x += __uint_as_float((unsigned)h.x << 16);
    acc.y += __uint_as_float((unsigned)h.y << 16);
    acc.z += __uint_as_float((unsigned)h.z << 16);
    acc.w += __uint_as_float((unsigned)h.w << 16);
  }

  // Matvec via width-16 shuffles (no LDS round-trip for rst).
  float4 res = *reinterpret_cast<const float4*>(b + j4);
#pragma unroll
  for (int i4 = 0; i4 < 16; ++i4) {
    float rx = __shfl(acc.x, i4, 16);
    float ry = __shfl(acc.y, i4, 16);
    float rz = __shfl(acc.z, i4, 16);
    float rw = __shfl(acc.w, i4, 16);
    const float4 w0 = *reinterpret_cast<const float4*>(Wt + ((i4 << 2) + 0) * D + j4);
    const float4 w1 = *reinterpret_cast<const float4*>(Wt + ((i4 << 2) + 1) * D + j4);
    const float4 w2 = *reinterpret_cast<const float4*>(Wt + ((i4 << 2) + 2) * D + j4);
    const float4 w3 = *reinterpret_cast<const float4*>(Wt + ((i4 << 2) + 3) * D + j4);
    res.x += rx * w0.x + ry * w1.x + rz * w2.x + rw * w3.x;
    res.y += rx * w0.y + ry * w1.y + rz * w2.y + rw * w3.y;
    res.z += rx * w0.z + ry * w1.z + rz * w2.z + rw * w3.z;
    res.w += rx * w0.w + ry * w1.w + rz * w2.w + rw * w3.w;
  }
  *reinterpret_cast<float4*>(out + (node << 6) + j4) = res;
}

extern "C" void kernel_launch(void* const* d_in, const int* in_sizes, int n_in,
                              void* d_out, int out_size, void* d_ws, size_t ws_size,
                              hipStream_t stream) {
  const float* feat = (const float*)d_in[0];
  const float* W    = (const float*)d_in[1];
  const float* b    = (const float*)d_in[2];
  const float* eps  = (const float*)d_in[3];
  const int*   src  = (const int*)d_in[4];
  const int*   dst  = (const int*)d_in[5];
  float* out = (float*)d_out;

  int* ws = (int*)d_ws;
  int* cnt2      = ws + WS_CNT2;
  int* noff      = ws + WS_NOFF;
  int* ndeg      = ws + WS_NDEG;
  unsigned* rbuf = (unsigned*)(ws + WS_RBUF);
  ushort* csr    = (ushort*)((char*)d_ws + WS_CSR_BYTE);
  ushort* hb     = (ushort*)((char*)d_ws + WS_HB_BYTE);

  hipLaunchKernelGGL(tobf16_kernel, dim3((N_NODES * D / 4 + 255) / 256), dim3(256),
                     0, stream, (const float4*)feat, hb);
  hipLaunchKernelGGL(bin_kernel, dim3(NBINB), dim3(1024), 0, stream,
                     src, dst, cnt2, rbuf);
  hipLaunchKernelGGL(compact_kernel, dim3(NREG), dim3(256), 0, stream,
                     cnt2, rbuf, csr, noff, ndeg);
  hipLaunchKernelGGL(gin_kernel, dim3(N_NODES / 16), dim3(256), 0, stream,
                     feat, hb, W, b, eps, noff, ndeg, csr, out);
}

// Round 8
// 112.775 us; speedup vs baseline: 2.6051x; 1.2159x over previous
//
#include <hip/hip_runtime.h>

constexpr int N_NODES = 50000;
constexpr int N_EDGES = 800000;
constexpr int D = 64;

constexpr int NREG = 256;    // destination regions (one gin block each)
constexpr int RSZ = 196;     // nodes per region (256*196 = 50176 >= 50000)
constexpr int EPB = 4096;    // edges per prep block
constexpr int NBINB = 196;   // ceil(800000/4096)
constexpr int CELLCAP = 64;  // per-(region,block) cell cap; mean 16, P(>64) ~ 1e-20
constexpr int RECAP = 4608;  // per-region edge cap; mean 3136, sigma 56 (26 sigma)

// Workspace layout:
//   cnt2 [NREG*NBINB] ints          at int 0          (200 KB)
//   rbuf [NREG*NBINB*CELLCAP] ints  at int 50176      (12.8 MB, 256B cells)
//   hb   [N_NODES*D] ushorts        at byte 13045760  (6.4 MB)
constexpr int WS_CNT2 = 0;
constexpr int WS_RBUF = 50176;
constexpr size_t WS_HB_BYTE = (size_t)(50176 + (size_t)NREG * NBINB * CELLCAP) * 4;

using vfloat4 = __attribute__((ext_vector_type(4))) float;  // native vec for NT ops

__device__ __forceinline__ ushort to_bf16(float x) {
  unsigned u = __float_as_uint(x);
  u += 0x7FFF + ((u >> 16) & 1);  // RNE
  return (ushort)(u >> 16);
}
__device__ __forceinline__ float from_bf16(ushort h) {
  return __uint_as_float((unsigned)h << 16);
}

// Fused: feat->bf16 conversion slice + edge binning into per-(region,block)
// cells. LDS cursor per region only (no sort here; gin sorts per region).
__global__ __launch_bounds__(1024) void prep_kernel(
    const float4* __restrict__ feat4, const int* __restrict__ src,
    const int* __restrict__ dst, ushort* __restrict__ hb,
    int* __restrict__ cnt2, unsigned* __restrict__ rbuf) {
  __shared__ int cur[NREG];
  int tid = threadIdx.x, blk = blockIdx.x;
  if (tid < NREG) cur[tid] = 0;

  // Start edge loads early; latency hidden behind the bf16 conversion.
  int e0 = blk * EPB + tid * 4;
  bool valid = (e0 + 4 <= N_EDGES);  // N_EDGES % 4 == 0
  int4 d4 = {0, 0, 0, 0}, s4 = {0, 0, 0, 0};
  if (valid) {
    d4 = *reinterpret_cast<const int4*>(dst + e0);
    s4 = *reinterpret_cast<const int4*>(src + e0);
  }

  // bf16 conversion: 4096 float4 per block (196*4096 >= 800000 float4s).
  int cb = blk * 4096 + tid;
#pragma unroll
  for (int k = 0; k < 4; ++k) {
    int t = cb + k * 1024;
    if (t < N_NODES * D / 4) {
      float4 f = feat4[t];
      ushort4 h;
      h.x = to_bf16(f.x); h.y = to_bf16(f.y);
      h.z = to_bf16(f.z); h.w = to_bf16(f.w);
      *reinterpret_cast<ushort4*>(hb + t * 4) = h;
    }
  }
  __syncthreads();

  if (valid) {
    const int dd[4] = {d4.x, d4.y, d4.z, d4.w};
    const int ss[4] = {s4.x, s4.y, s4.z, s4.w};
#pragma unroll
    for (int k = 0; k < 4; ++k) {
      int r = dd[k] / RSZ;  // magic-mul
      unsigned pk = ((unsigned)(dd[k] - r * RSZ) << 16) | (unsigned)ss[k];
      int p = atomicAdd(&cur[r], 1);
      if (p < CELLCAP)
        rbuf[(size_t)(r * NBINB + blk) * CELLCAP + p] = pk;
    }
  }
  __syncthreads();
  if (tid < NREG) {
    int c = cur[tid];
    cnt2[tid * NBINB + blk] = (c > CELLCAP) ? CELLCAP : c;
  }
}

// One block per region: gather region edges from cells into LDS, counting-
// sort by local node (all in LDS), then per-node bf16 gather + residual +
// Linear via width-16 shuffles. 1024 threads = 64 groups x 16 lanes.
__global__ __launch_bounds__(1024) void gin_kernel(
    const float* __restrict__ feat, const ushort* __restrict__ hb,
    const float* __restrict__ W, const float* __restrict__ b,
    const float* __restrict__ eps, const int* __restrict__ cnt2,
    const unsigned* __restrict__ rbuf, float* __restrict__ out) {
  __shared__ float Wt[D * D];          // 16 KB: Wt[i*64+o] = W[o*64+i]
  __shared__ unsigned ebuf[RECAP];     // 18.4 KB: unsorted region edges
  __shared__ ushort sorted[RECAP];     // 9.2 KB: src indices sorted by node
  __shared__ int cellstart[NBINB + 1];
  __shared__ int hist[RSZ], nstart[RSZ + 1], cursor[RSZ];
  __shared__ int scan_tmp[256];

  int tid = threadIdx.x, r = blockIdx.x;
  for (int q = tid; q < D * D; q += 1024) Wt[q] = W[((q & 63) << 6) + (q >> 6)];
  if (tid < RSZ) hist[tid] = 0;

  // Scan cell counts (contiguous 196-int read thanks to transposed cnt2).
  int c = (tid < NBINB) ? cnt2[r * NBINB + tid] : 0;
  if (tid < 256) scan_tmp[tid] = c;
  __syncthreads();
  for (int ofs = 1; ofs < 256; ofs <<= 1) {
    int v = 0;
    if (tid < 256 && tid >= ofs) v = scan_tmp[tid - ofs];
    __syncthreads();
    if (tid < 256) scan_tmp[tid] += v;
    __syncthreads();
  }
  if (tid < NBINB) cellstart[tid] = scan_tmp[tid] - c;
  if (tid == NBINB - 1) cellstart[NBINB] = scan_tmp[tid];
  __syncthreads();
  int T = cellstart[NBINB];
  if (T > RECAP) T = RECAP;  // statistically impossible

  // Concatenate cells into ebuf: 4 threads per cell, uint4 loads.
  {
    int blk2 = tid >> 2, sub = tid & 3;
    if (blk2 < NBINB) {
      int cs = cellstart[blk2];
      int cc = cellstart[blk2 + 1] - cs;
      const unsigned* cell = rbuf + (size_t)(r * NBINB + blk2) * CELLCAP;
      for (int i = sub * 4; i < cc; i += 16) {
        uint4 v = *reinterpret_cast<const uint4*>(cell + i);  // 16B-aligned
        if (cs + i + 0 < T && i + 0 < cc) ebuf[cs + i + 0] = v.x;
        if (cs + i + 1 < T && i + 1 < cc) ebuf[cs + i + 1] = v.y;
        if (cs + i + 2 < T && i + 2 < cc) ebuf[cs + i + 2] = v.z;
        if (cs + i + 3 < T && i + 3 < cc) ebuf[cs + i + 3] = v.w;
      }
    }
  }
  __syncthreads();

  // Histogram by local node, scan, scatter -> sorted (src as ushort).
  for (int e = tid; e < T; e += 1024) atomicAdd(&hist[ebuf[e] >> 16], 1);
  __syncthreads();
  if (tid < 256) scan_tmp[tid] = (tid < RSZ) ? hist[tid] : 0;
  __syncthreads();
  for (int ofs = 1; ofs < 256; ofs <<= 1) {
    int v = 0;
    if (tid < 256 && tid >= ofs) v = scan_tmp[tid - ofs];
    __syncthreads();
    if (tid < 256) scan_tmp[tid] += v;
    __syncthreads();
  }
  if (tid < RSZ) {
    int ex = scan_tmp[tid] - hist[tid];
    nstart[tid] = ex;
    cursor[tid] = ex;
  }
  if (tid == RSZ - 1) nstart[RSZ] = scan_tmp[tid];
  __syncthreads();
  for (int e = tid; e < T; e += 1024) {
    unsigned pk = ebuf[e];
    int p = atomicAdd(&cursor[pk >> 16], 1);
    sorted[p] = (ushort)(pk & 0xFFFFu);
  }
  __syncthreads();

  // Per-node gather + residual + matvec. Group g owns nodes g, g+64, ...
  int g = tid >> 4, j4 = (tid & 15) << 2;
  float s = 1.0f + eps[0];

  for (int n = g; n < RSZ; n += 64) {
    int node = r * RSZ + n;
    if (node >= N_NODES) continue;  // group-uniform

    // Nontemporal: don't let the fp32 feat stream evict hb from L2.
    vfloat4 fin = __builtin_nontemporal_load(
        reinterpret_cast<const vfloat4*>(feat + (node << 6) + j4));
    float4 acc;
    acc.x = fin.x * s; acc.y = fin.y * s; acc.z = fin.z * s; acc.w = fin.w * s;

    int e = nstart[n], e1 = nstart[n + 1];
    for (; e + 8 <= e1; e += 8) {
      int i0 = sorted[e + 0], i1 = sorted[e + 1], i2 = sorted[e + 2], i3 = sorted[e + 3];
      int i4_ = sorted[e + 4], i5 = sorted[e + 5], i6 = sorted[e + 6], i7 = sorted[e + 7];
      ushort4 h0 = *reinterpret_cast<const ushort4*>(hb + (i0 << 6) + j4);
      ushort4 h1 = *reinterpret_cast<const ushort4*>(hb + (i1 << 6) + j4);
      ushort4 h2 = *reinterpret_cast<const ushort4*>(hb + (i2 << 6) + j4);
      ushort4 h3 = *reinterpret_cast<const ushort4*>(hb + (i3 << 6) + j4);
      ushort4 h4 = *reinterpret_cast<const ushort4*>(hb + (i4_ << 6) + j4);
      ushort4 h5 = *reinterpret_cast<const ushort4*>(hb + (i5 << 6) + j4);
      ushort4 h6 = *reinterpret_cast<const ushort4*>(hb + (i6 << 6) + j4);
      ushort4 h7 = *reinterpret_cast<const ushort4*>(hb + (i7 << 6) + j4);
      acc.x += (from_bf16(h0.x) + from_bf16(h1.x)) + (from_bf16(h2.x) + from_bf16(h3.x))
             + (from_bf16(h4.x) + from_bf16(h5.x)) + (from_bf16(h6.x) + from_bf16(h7.x));
      acc.y += (from_bf16(h0.y) + from_bf16(h1.y)) + (from_bf16(h2.y) + from_bf16(h3.y))
             + (from_bf16(h4.y) + from_bf16(h5.y)) + (from_bf16(h6.y) + from_bf16(h7.y));
      acc.z += (from_bf16(h0.z) + from_bf16(h1.z)) + (from_bf16(h2.z) + from_bf16(h3.z))
             + (from_bf16(h4.z) + from_bf16(h5.z)) + (from_bf16(h6.z) + from_bf16(h7.z));
      acc.w += (from_bf16(h0.w) + from_bf16(h1.w)) + (from_bf16(h2.w) + from_bf16(h3.w))
             + (from_bf16(h4.w) + from_bf16(h5.w)) + (from_bf16(h6.w) + from_bf16(h7.w));
    }
    for (; e < e1; ++e) {
      int sn = sorted[e];
      ushort4 h = *reinterpret_cast<const ushort4*>(hb + (sn << 6) + j4);
      acc.x += from_bf16(h.x); acc.y += from_bf16(h.y);
      acc.z += from_bf16(h.z); acc.w += from_bf16(h.w);
    }

    float4 res = *reinterpret_cast<const float4*>(b + j4);
#pragma unroll
    for (int i4 = 0; i4 < 16; ++i4) {
      float rx = __shfl(acc.x, i4, 16);
      float ry = __shfl(acc.y, i4, 16);
      float rz = __shfl(acc.z, i4, 16);
      float rw = __shfl(acc.w, i4, 16);
      const float4 w0 = *reinterpret_cast<const float4*>(Wt + ((i4 << 2) + 0) * D + j4);
      const float4 w1 = *reinterpret_cast<const float4*>(Wt + ((i4 << 2) + 1) * D + j4);
      const float4 w2 = *reinterpret_cast<const float4*>(Wt + ((i4 << 2) + 2) * D + j4);
      const float4 w3 = *reinterpret_cast<const float4*>(Wt + ((i4 << 2) + 3) * D + j4);
      res.x += rx * w0.x + ry * w1.x + rz * w2.x + rw * w3.x;
      res.y += rx * w0.y + ry * w1.y + rz * w2.y + rw * w3.y;
      res.z += rx * w0.z + ry * w1.z + rz * w2.z + rw * w3.z;
      res.w += rx * w0.w + ry * w1.w + rz * w2.w + rw * w3.w;
    }
    vfloat4 vres;
    vres.x = res.x; vres.y = res.y; vres.z = res.z; vres.w = res.w;
    __builtin_nontemporal_store(
        vres, reinterpret_cast<vfloat4*>(out + (node << 6) + j4));
  }
}

extern "C" void kernel_launch(void* const* d_in, const int* in_sizes, int n_in,
                              void* d_out, int out_size, void* d_ws, size_t ws_size,
                              hipStream_t stream) {
  const float* feat = (const float*)d_in[0];
  const float* W    = (const float*)d_in[1];
  const float* b    = (const float*)d_in[2];
  const float* eps  = (const float*)d_in[3];
  const int*   src  = (const int*)d_in[4];
  const int*   dst  = (const int*)d_in[5];
  float* out = (float*)d_out;

  int* ws = (int*)d_ws;
  int* cnt2      = ws + WS_CNT2;
  unsigned* rbuf = (unsigned*)(ws + WS_RBUF);
  ushort* hb     = (ushort*)((char*)d_ws + WS_HB_BYTE);

  hipLaunchKernelGGL(prep_kernel, dim3(NBINB), dim3(1024), 0, stream,
                     (const float4*)feat, src, dst, hb, cnt2, rbuf);
  hipLaunchKernelGGL(gin_kernel, dim3(NREG), dim3(1024), 0, stream,
                     feat, hb, W, b, eps, cnt2, rbuf, out);
}